// Round 2
// baseline (1129.314 us; speedup 1.0000x reference)
//
#include <hip/hip_runtime.h>

#define Bn 4
#define Cn 256
#define CQn 64
#define Nn 4096

using f32x4  = __attribute__((ext_vector_type(4))) float;
using half8  = __attribute__((ext_vector_type(8))) _Float16;

#define MFMA_F16(a, b, c)  __builtin_amdgcn_mfma_f32_16x16x32_f16((a), (b), (c), 0, 0, 0)

// ---------------------------------------------------------------------------
// P1: q/k1/k2 projections. out_t[b][n][o] = sum_c W[o][c] x[b][c][n] + bias[o]
// stored f16, layout (B, N, 64). blockIdx.z selects proj (0:q<-x3, 1:k1<-x1, 2:k2<-x2).
// A[n][c] = x^T (scattered 4B loads), B[c][o] = W^T (contig 32B from W rows).
// ---------------------------------------------------------------------------
__global__ __launch_bounds__(256) void proj_qk(
    const float* __restrict__ x1, const float* __restrict__ x2,
    const float* __restrict__ x3,
    const float* __restrict__ Wq, const float* __restrict__ bq,
    const float* __restrict__ Wk, const float* __restrict__ bk,
    const float* __restrict__ Wk2, const float* __restrict__ bk2,
    _Float16* __restrict__ qt, _Float16* __restrict__ k1t, _Float16* __restrict__ k2t)
{
  const int p = blockIdx.z;
  const float* x    = (p == 0) ? x3 : (p == 1) ? x1 : x2;
  const float* W    = (p == 0) ? Wq : (p == 1) ? Wk : Wk2;
  const float* bias = (p == 0) ? bq : (p == 1) ? bk : bk2;
  _Float16* out     = (p == 0) ? qt : (p == 1) ? k1t : k2t;

  const int b = blockIdx.y;
  const int n0 = blockIdx.x * 64;
  const int tid = threadIdx.x;
  const int w = tid >> 6, lane = tid & 63, quad = lane >> 4, l16 = lane & 15;
  const int n_row = n0 + w * 16 + l16;  // A row
  const float* xb = x + (size_t)b * Cn * Nn;

  f32x4 acc[4] = {};
  for (int kst = 0; kst < 8; ++kst) {
    const int c = kst * 32 + quad * 8;
    half8 a;
#pragma unroll
    for (int j = 0; j < 8; ++j) a[j] = (_Float16)xb[(size_t)(c + j) * Nn + n_row];
#pragma unroll
    for (int s = 0; s < 4; ++s) {
      const int o = s * 16 + l16;
      const f32x4 w0 = *(const f32x4*)(W + (size_t)o * Cn + c);
      const f32x4 w1 = *(const f32x4*)(W + (size_t)o * Cn + c + 4);
      half8 bf;
#pragma unroll
      for (int j = 0; j < 4; ++j) { bf[j] = (_Float16)w0[j]; bf[4 + j] = (_Float16)w1[j]; }
      acc[s] = MFMA_F16(a, bf, acc[s]);
    }
  }
#pragma unroll
  for (int s = 0; s < 4; ++s) {
    const int o = s * 16 + l16;
    const float bb = bias[o];
#pragma unroll
    for (int r = 0; r < 4; ++r) {
      const int n = n0 + w * 16 + quad * 4 + r;  // D row
      out[((size_t)b * Nn + n) * CQn + o] = (_Float16)(acc[s][r] + bb);
    }
  }
}

// ---------------------------------------------------------------------------
// P2: v/vt projections. out[b][o][n] = sum_c W[o][c] x[b][c][n] + bias[o]
// f16, natural layout (B, C, N). blockIdx.z: 0: v<-x3, 1: vt<-xt.
// A = W rows (contig), B = x columns (scattered 4B).
// Block: 256 o (wave w: o in [64w,64w+64)) x 32 n.
// ---------------------------------------------------------------------------
__global__ __launch_bounds__(256) void proj_v(
    const float* __restrict__ x3, const float* __restrict__ xt,
    const float* __restrict__ Wv, const float* __restrict__ bv,
    const float* __restrict__ Wv2, const float* __restrict__ bv2,
    _Float16* __restrict__ v, _Float16* __restrict__ vt)
{
  const int p = blockIdx.z;
  const float* x    = p ? xt : x3;
  const float* W    = p ? Wv2 : Wv;
  const float* bias = p ? bv2 : bv;
  _Float16* out     = p ? vt : v;

  const int b = blockIdx.y;
  const int n0 = blockIdx.x * 32;
  const int tid = threadIdx.x;
  const int w = tid >> 6, lane = tid & 63, quad = lane >> 4, l16 = lane & 15;
  const float* xb = x + (size_t)b * Cn * Nn;

  f32x4 acc[4][2] = {};
  for (int kst = 0; kst < 8; ++kst) {
    const int c = kst * 32 + quad * 8;
    half8 bfr[2];
#pragma unroll
    for (int t = 0; t < 2; ++t) {
      const int n = n0 + t * 16 + l16;
#pragma unroll
      for (int j = 0; j < 8; ++j) bfr[t][j] = (_Float16)xb[(size_t)(c + j) * Nn + n];
    }
#pragma unroll
    for (int s = 0; s < 4; ++s) {
      const int o = w * 64 + s * 16 + l16;
      const f32x4 w0 = *(const f32x4*)(W + (size_t)o * Cn + c);
      const f32x4 w1 = *(const f32x4*)(W + (size_t)o * Cn + c + 4);
      half8 a;
#pragma unroll
      for (int j = 0; j < 4; ++j) { a[j] = (_Float16)w0[j]; a[4 + j] = (_Float16)w1[j]; }
#pragma unroll
      for (int t = 0; t < 2; ++t) acc[s][t] = MFMA_F16(a, bfr[t], acc[s][t]);
    }
  }
#pragma unroll
  for (int s = 0; s < 4; ++s) {
#pragma unroll
    for (int r = 0; r < 4; ++r) {
      const int o = w * 64 + s * 16 + quad * 4 + r;  // D row
      const float bb = bias[o];
#pragma unroll
      for (int t = 0; t < 2; ++t) {
        const int n = n0 + t * 16 + l16;  // D col
        out[((size_t)b * Cn + o) * Nn + n] = (_Float16)(acc[s][t][r] + bb);
      }
    }
  }
}

// ---------------------------------------------------------------------------
// K2: S1/S2 GEMM + softmax(softmax(S1)+softmax(S2)), 64 rows per block.
// No max subtraction needed: |S| <~ 30 (exp fits fp32), and a1+a2 in (0,2].
// loop1: l1 = sum exp(S1), l2 = sum exp(S2)
// loop2: p = exp(exp(S1-log l1) + exp(S2-log l2)), store f32 in d_out, acc L
// loop3: attn = p / L, in place (f32).
// ---------------------------------------------------------------------------
__global__ __launch_bounds__(256) void attn_softmax(
    const _Float16* __restrict__ qt, const _Float16* __restrict__ k1t,
    const _Float16* __restrict__ k2t, float* __restrict__ attn)
{
  const int i = blockIdx.x;
  const int b = (i & 7) >> 1;                      // XCD-pair per batch
  const int nt = ((i >> 3) << 1) | (i & 1);
  const int n0 = nt * 64;
  const int tid = threadIdx.x;
  const int w = tid >> 6, lane = tid & 63, quad = lane >> 4, l16 = lane & 15;

  const _Float16* qrow = qt + ((size_t)b * Nn + n0 + w * 16 + l16) * CQn;
  const half8 aq0 = *(const half8*)(qrow + quad * 8);
  const half8 aq1 = *(const half8*)(qrow + 32 + quad * 8);
  const _Float16* k1b = k1t + (size_t)b * Nn * CQn;
  const _Float16* k2b = k2t + (size_t)b * Nn * CQn;

  float l1a[4] = {0.f, 0.f, 0.f, 0.f}, l2a[4] = {0.f, 0.f, 0.f, 0.f};
  for (int m0 = 0; m0 < Nn; m0 += 64) {
#pragma unroll
    for (int s = 0; s < 4; ++s) {
      const int m = m0 + s * 16 + l16;
      const half8 b1a = *(const half8*)(k1b + (size_t)m * CQn + quad * 8);
      const half8 b1b = *(const half8*)(k1b + (size_t)m * CQn + 32 + quad * 8);
      f32x4 S1 = {};
      S1 = MFMA_F16(aq0, b1a, S1);
      S1 = MFMA_F16(aq1, b1b, S1);
      const half8 b2a = *(const half8*)(k2b + (size_t)m * CQn + quad * 8);
      const half8 b2b = *(const half8*)(k2b + (size_t)m * CQn + 32 + quad * 8);
      f32x4 S2 = {};
      S2 = MFMA_F16(aq0, b2a, S2);
      S2 = MFMA_F16(aq1, b2b, S2);
#pragma unroll
      for (int r = 0; r < 4; ++r) {
        l1a[r] += __expf(S1[r]);
        l2a[r] += __expf(S2[r]);
      }
    }
  }
#pragma unroll
  for (int r = 0; r < 4; ++r) {
#pragma unroll
    for (int off = 1; off < 16; off <<= 1) {
      l1a[r] += __shfl_xor(l1a[r], off);
      l2a[r] += __shfl_xor(l2a[r], off);
    }
  }
  float lg1[4], lg2[4];
#pragma unroll
  for (int r = 0; r < 4; ++r) { lg1[r] = __logf(l1a[r]); lg2[r] = __logf(l2a[r]); }

  float La[4] = {0.f, 0.f, 0.f, 0.f};
  for (int m0 = 0; m0 < Nn; m0 += 64) {
#pragma unroll
    for (int s = 0; s < 4; ++s) {
      const int m = m0 + s * 16 + l16;
      const half8 b1a = *(const half8*)(k1b + (size_t)m * CQn + quad * 8);
      const half8 b1b = *(const half8*)(k1b + (size_t)m * CQn + 32 + quad * 8);
      f32x4 S1 = {};
      S1 = MFMA_F16(aq0, b1a, S1);
      S1 = MFMA_F16(aq1, b1b, S1);
      const half8 b2a = *(const half8*)(k2b + (size_t)m * CQn + quad * 8);
      const half8 b2b = *(const half8*)(k2b + (size_t)m * CQn + 32 + quad * 8);
      f32x4 S2 = {};
      S2 = MFMA_F16(aq0, b2a, S2);
      S2 = MFMA_F16(aq1, b2b, S2);
#pragma unroll
      for (int r = 0; r < 4; ++r) {
        const float a1 = __expf(S1[r] - lg1[r]);
        const float a2 = __expf(S2[r] - lg2[r]);
        const float pp = __expf(a1 + a2);
        La[r] += pp;
        const int n = n0 + w * 16 + quad * 4 + r;
        attn[((size_t)b * Nn + n) * Nn + m] = pp;
      }
    }
  }
#pragma unroll
  for (int r = 0; r < 4; ++r) {
#pragma unroll
    for (int off = 1; off < 16; off <<= 1) La[r] += __shfl_xor(La[r], off);
  }
  __shared__ float rLs[64];
  if (l16 == 0) {
#pragma unroll
    for (int r = 0; r < 4; ++r) rLs[w * 16 + quad * 4 + r] = 1.0f / La[r];
  }
  __syncthreads();

  // rescale in place (f32)
  for (int it = 0; it < 256; ++it) {
    const int vid = it * 256 + tid;     // 65536 float4-groups
    const int row = vid >> 10;          // 0..63
    const int m4 = (vid & 1023) << 2;   // 0..4092
    const float rl = rLs[row];
    float* pr = attn + ((size_t)b * Nn + n0 + row) * Nn + m4;
    f32x4 h = *(const f32x4*)pr;
    h[0] *= rl; h[1] *= rl; h[2] *= rl; h[3] *= rl;
    *(f32x4*)pr = h;
  }
}

// ---------------------------------------------------------------------------
// K3: out1[c,n] = sum_m v[c,m] * attn[n,m]  (+ same with vt), fused epilogue.
// A = v rows (contig f16 16B), B = attn rows (f32, converted to f16 frags).
// Block: all 256 c (wave w: [64w,64w+64)) x 64 n -> attn read exactly once.
// ---------------------------------------------------------------------------
__global__ __launch_bounds__(256, 1) void pv_epilogue(
    const _Float16* __restrict__ v, const _Float16* __restrict__ vtb,
    const float* __restrict__ attn,
    const float* __restrict__ x3, const float* __restrict__ xt,
    const float* __restrict__ gamma, const float* __restrict__ gamma2,
    float* __restrict__ out1, float* __restrict__ out2)
{
  const int i = blockIdx.x;
  const int b = (i & 7) >> 1;
  const int nt = ((i >> 3) << 1) | (i & 1);
  const int n0 = nt * 64;
  const int tid = threadIdx.x;
  const int w = tid >> 6, lane = tid & 63, quad = lane >> 4, l16 = lane & 15;

  const _Float16* vb = v + (size_t)b * Cn * Nn;
  const _Float16* vtb2 = vtb + (size_t)b * Cn * Nn;
  const float* ab = attn + (size_t)b * Nn * Nn;

  f32x4 acc1[4][4] = {};
  f32x4 acc2[4][4] = {};
  for (int m0 = 0; m0 < Nn; m0 += 32) {
    const int mq = m0 + quad * 8;
    half8 Bf[4];
#pragma unroll
    for (int t = 0; t < 4; ++t) {
      const float* ar = ab + (size_t)(n0 + t * 16 + l16) * Nn + mq;
      const f32x4 a0 = *(const f32x4*)ar;
      const f32x4 a1 = *(const f32x4*)(ar + 4);
#pragma unroll
      for (int j = 0; j < 4; ++j) { Bf[t][j] = (_Float16)a0[j]; Bf[t][4 + j] = (_Float16)a1[j]; }
    }
#pragma unroll
    for (int s = 0; s < 4; ++s) {
      const int c = w * 64 + s * 16 + l16;
      const half8 A1 = *(const half8*)(vb + (size_t)c * Nn + mq);
      const half8 A2 = *(const half8*)(vtb2 + (size_t)c * Nn + mq);
#pragma unroll
      for (int t = 0; t < 4; ++t) {
        acc1[s][t] = MFMA_F16(A1, Bf[t], acc1[s][t]);
        acc2[s][t] = MFMA_F16(A2, Bf[t], acc2[s][t]);
      }
    }
  }
  const float g1 = gamma[0];
  const float g2 = gamma2[0];
#pragma unroll
  for (int s = 0; s < 4; ++s) {
#pragma unroll
    for (int t = 0; t < 4; ++t) {
#pragma unroll
      for (int r = 0; r < 4; ++r) {
        const int c = w * 64 + s * 16 + quad * 4 + r;  // D row
        const int n = n0 + t * 16 + l16;               // D col
        const size_t idx = ((size_t)b * Cn + c) * Nn + n;
        out1[idx] = g1 * acc1[s][t][r] + x3[idx];
        out2[idx] = g2 * acc2[s][t][r] + xt[idx];
      }
    }
  }
}

// ---------------------------------------------------------------------------
extern "C" void kernel_launch(void* const* d_in, const int* in_sizes, int n_in,
                              void* d_out, int out_size, void* d_ws, size_t ws_size,
                              hipStream_t stream) {
  const float* x1  = (const float*)d_in[0];
  const float* x2  = (const float*)d_in[1];
  const float* x3  = (const float*)d_in[2];
  const float* xt  = (const float*)d_in[3];
  const float* Wq  = (const float*)d_in[4];
  const float* bq  = (const float*)d_in[5];
  const float* Wk  = (const float*)d_in[6];
  const float* bk  = (const float*)d_in[7];
  const float* Wk2 = (const float*)d_in[8];
  const float* bk2 = (const float*)d_in[9];
  const float* Wv  = (const float*)d_in[10];
  const float* bv  = (const float*)d_in[11];
  const float* Wv2 = (const float*)d_in[12];
  const float* bv2 = (const float*)d_in[13];
  const float* gamma  = (const float*)d_in[14];
  const float* gamma2 = (const float*)d_in[15];

  float* outp = (float*)d_out;
  float* attn = outp;                                   // B*N*N
  float* out1 = outp + (size_t)Bn * Nn * Nn;            // B*C*N
  float* out2 = out1 + (size_t)Bn * Cn * Nn;

  _Float16* qt  = (_Float16*)d_ws;                      // B*N*CQ f16
  _Float16* k1t = qt + (size_t)Bn * Nn * CQn;
  _Float16* k2t = k1t + (size_t)Bn * Nn * CQn;
  _Float16* v   = k2t + (size_t)Bn * Nn * CQn;          // B*C*N f16
  _Float16* vt  = v + (size_t)Bn * Cn * Nn;

  proj_qk<<<dim3(Nn / 64, Bn, 3), 256, 0, stream>>>(x1, x2, x3, Wq, bq, Wk, bk, Wk2, bk2,
                                                    qt, k1t, k2t);
  proj_v<<<dim3(Nn / 32, Bn, 2), 256, 0, stream>>>(x3, xt, Wv, bv, Wv2, bv2, v, vt);
  attn_softmax<<<dim3(256), 256, 0, stream>>>(qt, k1t, k2t, attn);
  pv_epilogue<<<dim3(256), 256, 0, stream>>>(v, vt, attn, x3, xt, gamma, gamma2, out1, out2);
}

// Round 3
// 1119.559 us; speedup vs baseline: 1.0087x; 1.0087x over previous
//
#include <hip/hip_runtime.h>

#define Bn 4
#define Cn 256
#define CQn 64
#define Nn 4096

using f32x4  = __attribute__((ext_vector_type(4))) float;
using half8  = __attribute__((ext_vector_type(8))) _Float16;

#define MFMA_F16(a, b, c)  __builtin_amdgcn_mfma_f32_16x16x32_f16((a), (b), (c), 0, 0, 0)

// ---------------------------------------------------------------------------
// P1: q/k1/k2 projections. out_t[b][n][o] = sum_c W[o][c] x[b][c][n] + bias[o]
// stored f16, layout (B, N, 64). blockIdx.z selects proj (0:q<-x3, 1:k1<-x1, 2:k2<-x2).
// ---------------------------------------------------------------------------
__global__ __launch_bounds__(256) void proj_qk(
    const float* __restrict__ x1, const float* __restrict__ x2,
    const float* __restrict__ x3,
    const float* __restrict__ Wq, const float* __restrict__ bq,
    const float* __restrict__ Wk, const float* __restrict__ bk,
    const float* __restrict__ Wk2, const float* __restrict__ bk2,
    _Float16* __restrict__ qt, _Float16* __restrict__ k1t, _Float16* __restrict__ k2t)
{
  const int p = blockIdx.z;
  const float* x    = (p == 0) ? x3 : (p == 1) ? x1 : x2;
  const float* W    = (p == 0) ? Wq : (p == 1) ? Wk : Wk2;
  const float* bias = (p == 0) ? bq : (p == 1) ? bk : bk2;
  _Float16* out     = (p == 0) ? qt : (p == 1) ? k1t : k2t;

  const int b = blockIdx.y;
  const int n0 = blockIdx.x * 64;
  const int tid = threadIdx.x;
  const int w = tid >> 6, lane = tid & 63, quad = lane >> 4, l16 = lane & 15;
  const int n_row = n0 + w * 16 + l16;  // A row
  const float* xb = x + (size_t)b * Cn * Nn;

  f32x4 acc[4] = {};
  for (int kst = 0; kst < 8; ++kst) {
    const int c = kst * 32 + quad * 8;
    half8 a;
#pragma unroll
    for (int j = 0; j < 8; ++j) a[j] = (_Float16)xb[(size_t)(c + j) * Nn + n_row];
#pragma unroll
    for (int s = 0; s < 4; ++s) {
      const int o = s * 16 + l16;
      const f32x4 w0 = *(const f32x4*)(W + (size_t)o * Cn + c);
      const f32x4 w1 = *(const f32x4*)(W + (size_t)o * Cn + c + 4);
      half8 bf;
#pragma unroll
      for (int j = 0; j < 4; ++j) { bf[j] = (_Float16)w0[j]; bf[4 + j] = (_Float16)w1[j]; }
      acc[s] = MFMA_F16(a, bf, acc[s]);
    }
  }
#pragma unroll
  for (int s = 0; s < 4; ++s) {
    const int o = s * 16 + l16;
    const float bb = bias[o];
#pragma unroll
    for (int r = 0; r < 4; ++r) {
      const int n = n0 + w * 16 + quad * 4 + r;  // D row
      out[((size_t)b * Nn + n) * CQn + o] = (_Float16)(acc[s][r] + bb);
    }
  }
}

// ---------------------------------------------------------------------------
// P2: v/vt projections. out[b][o][n] = sum_c W[o][c] x[b][c][n] + bias[o]
// f16, natural layout (B, C, N). blockIdx.z: 0: v<-x3, 1: vt<-xt.
// ---------------------------------------------------------------------------
__global__ __launch_bounds__(256) void proj_v(
    const float* __restrict__ x3, const float* __restrict__ xt,
    const float* __restrict__ Wv, const float* __restrict__ bv,
    const float* __restrict__ Wv2, const float* __restrict__ bv2,
    _Float16* __restrict__ v, _Float16* __restrict__ vt)
{
  const int p = blockIdx.z;
  const float* x    = p ? xt : x3;
  const float* W    = p ? Wv2 : Wv;
  const float* bias = p ? bv2 : bv;
  _Float16* out     = p ? vt : v;

  const int b = blockIdx.y;
  const int n0 = blockIdx.x * 32;
  const int tid = threadIdx.x;
  const int w = tid >> 6, lane = tid & 63, quad = lane >> 4, l16 = lane & 15;
  const float* xb = x + (size_t)b * Cn * Nn;

  f32x4 acc[4][2] = {};
  for (int kst = 0; kst < 8; ++kst) {
    const int c = kst * 32 + quad * 8;
    half8 bfr[2];
#pragma unroll
    for (int t = 0; t < 2; ++t) {
      const int n = n0 + t * 16 + l16;
#pragma unroll
      for (int j = 0; j < 8; ++j) bfr[t][j] = (_Float16)xb[(size_t)(c + j) * Nn + n];
    }
#pragma unroll
    for (int s = 0; s < 4; ++s) {
      const int o = w * 64 + s * 16 + l16;
      const f32x4 w0 = *(const f32x4*)(W + (size_t)o * Cn + c);
      const f32x4 w1 = *(const f32x4*)(W + (size_t)o * Cn + c + 4);
      half8 a;
#pragma unroll
      for (int j = 0; j < 4; ++j) { a[j] = (_Float16)w0[j]; a[4 + j] = (_Float16)w1[j]; }
#pragma unroll
      for (int t = 0; t < 2; ++t) acc[s][t] = MFMA_F16(a, bfr[t], acc[s][t]);
    }
  }
#pragma unroll
  for (int s = 0; s < 4; ++s) {
#pragma unroll
    for (int r = 0; r < 4; ++r) {
      const int o = w * 64 + s * 16 + quad * 4 + r;  // D row
      const float bb = bias[o];
#pragma unroll
      for (int t = 0; t < 2; ++t) {
        const int n = n0 + t * 16 + l16;  // D col
        out[((size_t)b * Cn + o) * Nn + n] = (_Float16)(acc[s][t][r] + bb);
      }
    }
  }
}

// ---------------------------------------------------------------------------
// Fused: S GEMM + double-softmax + attn write + PV + epilogue.
// Block = (batch b, 16 attn rows). 4 waves each own a 1024-wide m-chunk.
//  pass1: l1=sum exp(S1), l2=sum exp(S2) over own chunk; LDS-reduce.
//  pass2: p = exp(exp(S1-lg1)+exp(S2-lg2)) -> f32 to attn region; acc L; reduce.
//  pass3: re-read own p (L2-hot), scale by 1/L, store normalized attn, and
//         MFMA-accumulate out[256c x 16n] (p tile is already B-fragment layout:
//         lane reads row n=l16, m=quad*8..+8). Cross-wave LDS reduce, +residual.
// ---------------------------------------------------------------------------
__global__ __launch_bounds__(256) void attn_fused(
    const _Float16* __restrict__ qt, const _Float16* __restrict__ k1t,
    const _Float16* __restrict__ k2t, const _Float16* __restrict__ v,
    const _Float16* __restrict__ vt,
    const float* __restrict__ x3, const float* __restrict__ xt,
    const float* __restrict__ gamma, const float* __restrict__ gamma2,
    float* __restrict__ attn, float* __restrict__ out1, float* __restrict__ out2)
{
  __shared__ float red[4][2][16];
  __shared__ float rLs[16];
  __shared__ float accbuf[4][256][17];   // pad 17: conflict-light staging

  const int i = blockIdx.x;
  const int b = (i & 7) >> 1;                      // batch pinned to XCD pair
  const int nt = ((i >> 3) << 1) | (i & 1);        // 0..255
  const int n0 = nt * 16;
  const int tid = threadIdx.x;
  const int w = tid >> 6, lane = tid & 63, quad = lane >> 4, l16 = lane & 15;
  const int m_lo = w * 1024;                       // this wave's m-chunk

  const _Float16* qrow = qt + ((size_t)b * Nn + n0 + l16) * CQn;
  const half8 aq0 = *(const half8*)(qrow + quad * 8);
  const half8 aq1 = *(const half8*)(qrow + 32 + quad * 8);
  const _Float16* k1b = k1t + (size_t)b * Nn * CQn;
  const _Float16* k2b = k2t + (size_t)b * Nn * CQn;
  float* pb = attn + ((size_t)b * Nn + n0) * Nn;   // block's 16 rows

  // ---- pass 1: row sums of exp(S1), exp(S2) over own m-chunk
  float l1a[4] = {0.f, 0.f, 0.f, 0.f}, l2a[4] = {0.f, 0.f, 0.f, 0.f};
#pragma unroll 4
  for (int mi = 0; mi < 64; ++mi) {
    const int m0 = m_lo + mi * 16;
    const _Float16* k1r = k1b + (size_t)(m0 + l16) * CQn;
    const _Float16* k2r = k2b + (size_t)(m0 + l16) * CQn;
    f32x4 S1 = {};
    S1 = MFMA_F16(aq0, *(const half8*)(k1r + quad * 8), S1);
    S1 = MFMA_F16(aq1, *(const half8*)(k1r + 32 + quad * 8), S1);
    f32x4 S2 = {};
    S2 = MFMA_F16(aq0, *(const half8*)(k2r + quad * 8), S2);
    S2 = MFMA_F16(aq1, *(const half8*)(k2r + 32 + quad * 8), S2);
#pragma unroll
    for (int r = 0; r < 4; ++r) { l1a[r] += __expf(S1[r]); l2a[r] += __expf(S2[r]); }
  }
#pragma unroll
  for (int r = 0; r < 4; ++r) {
#pragma unroll
    for (int off = 1; off < 16; off <<= 1) {
      l1a[r] += __shfl_xor(l1a[r], off);
      l2a[r] += __shfl_xor(l2a[r], off);
    }
  }
  if (l16 == 0) {
#pragma unroll
    for (int r = 0; r < 4; ++r) { red[w][0][quad * 4 + r] = l1a[r]; red[w][1][quad * 4 + r] = l2a[r]; }
  }
  __syncthreads();
  float lg1[4], lg2[4];
#pragma unroll
  for (int r = 0; r < 4; ++r) {
    const int n = quad * 4 + r;
    lg1[r] = __logf(red[0][0][n] + red[1][0][n] + red[2][0][n] + red[3][0][n]);
    lg2[r] = __logf(red[0][1][n] + red[1][1][n] + red[2][1][n] + red[3][1][n]);
  }
  __syncthreads();   // everyone has lg before red is reused for L

  // ---- pass 2: write unnormalized p (f32), accumulate L
  float La[4] = {0.f, 0.f, 0.f, 0.f};
#pragma unroll 4
  for (int mi = 0; mi < 64; ++mi) {
    const int m0 = m_lo + mi * 16;
    const _Float16* k1r = k1b + (size_t)(m0 + l16) * CQn;
    const _Float16* k2r = k2b + (size_t)(m0 + l16) * CQn;
    f32x4 S1 = {};
    S1 = MFMA_F16(aq0, *(const half8*)(k1r + quad * 8), S1);
    S1 = MFMA_F16(aq1, *(const half8*)(k1r + 32 + quad * 8), S1);
    f32x4 S2 = {};
    S2 = MFMA_F16(aq0, *(const half8*)(k2r + quad * 8), S2);
    S2 = MFMA_F16(aq1, *(const half8*)(k2r + 32 + quad * 8), S2);
#pragma unroll
    for (int r = 0; r < 4; ++r) {
      const float a1 = __expf(S1[r] - lg1[r]);
      const float a2 = __expf(S2[r] - lg2[r]);
      const float pp = __expf(a1 + a2);
      La[r] += pp;
      pb[(size_t)(quad * 4 + r) * Nn + m0 + l16] = pp;
    }
  }
#pragma unroll
  for (int r = 0; r < 4; ++r) {
#pragma unroll
    for (int off = 1; off < 16; off <<= 1) La[r] += __shfl_xor(La[r], off);
  }
  if (l16 == 0) {
#pragma unroll
    for (int r = 0; r < 4; ++r) red[w][0][quad * 4 + r] = La[r];
  }
  __syncthreads();
  if (tid < 16) rLs[tid] = 1.0f / (red[0][0][tid] + red[1][0][tid] + red[2][0][tid] + red[3][0][tid]);
  __syncthreads();

  // ---- pass 3: normalize+write attn, fused PV (out[256c x 16n] per block)
  const float rl = rLs[l16];
  const _Float16* vb  = v  + (size_t)b * Cn * Nn;
  const _Float16* vtb = vt + (size_t)b * Cn * Nn;
  f32x4 acc1[16], acc2[16];
#pragma unroll
  for (int s = 0; s < 16; ++s) { acc1[s] = (f32x4){}; acc2[s] = (f32x4){}; }

  for (int mi = 0; mi < 32; ++mi) {
    const int m0 = m_lo + mi * 32;
    float* pr = pb + (size_t)l16 * Nn + m0 + quad * 8;
    f32x4 p0 = *(const f32x4*)pr;
    f32x4 p1 = *(const f32x4*)(pr + 4);
#pragma unroll
    for (int j = 0; j < 4; ++j) { p0[j] *= rl; p1[j] *= rl; }
    *(f32x4*)pr = p0;
    *(f32x4*)(pr + 4) = p1;
    half8 Bf;
#pragma unroll
    for (int j = 0; j < 4; ++j) { Bf[j] = (_Float16)p0[j]; Bf[4 + j] = (_Float16)p1[j]; }
#pragma unroll
    for (int s = 0; s < 16; ++s) {
      const half8 A1 = *(const half8*)(vb + (size_t)(s * 16 + l16) * Nn + m0 + quad * 8);
      acc1[s] = MFMA_F16(A1, Bf, acc1[s]);
    }
#pragma unroll
    for (int s = 0; s < 16; ++s) {
      const half8 A2 = *(const half8*)(vtb + (size_t)(s * 16 + l16) * Nn + m0 + quad * 8);
      acc2[s] = MFMA_F16(A2, Bf, acc2[s]);
    }
  }

  // ---- cross-wave reduce + epilogue (out1 then out2, reusing accbuf)
#pragma unroll
  for (int s = 0; s < 16; ++s) {
#pragma unroll
    for (int r = 0; r < 4; ++r) accbuf[w][s * 16 + quad * 4 + r][l16] = acc1[s][r];
  }
  __syncthreads();
  {
    const float g1 = gamma[0];
    const int c = tid;
    const size_t base = ((size_t)b * Cn + c) * Nn + n0;
#pragma unroll
    for (int g = 0; g < 4; ++g) {
      f32x4 o;
#pragma unroll
      for (int j = 0; j < 4; ++j) {
        const int n = g * 4 + j;
        const float s = accbuf[0][c][n] + accbuf[1][c][n] + accbuf[2][c][n] + accbuf[3][c][n];
        o[j] = g1 * s + x3[base + n];
      }
      *(f32x4*)(out1 + base + g * 4) = o;
    }
  }
  __syncthreads();
#pragma unroll
  for (int s = 0; s < 16; ++s) {
#pragma unroll
    for (int r = 0; r < 4; ++r) accbuf[w][s * 16 + quad * 4 + r][l16] = acc2[s][r];
  }
  __syncthreads();
  {
    const float g2 = gamma2[0];
    const int c = tid;
    const size_t base = ((size_t)b * Cn + c) * Nn + n0;
#pragma unroll
    for (int g = 0; g < 4; ++g) {
      f32x4 o;
#pragma unroll
      for (int j = 0; j < 4; ++j) {
        const int n = g * 4 + j;
        const float s = accbuf[0][c][n] + accbuf[1][c][n] + accbuf[2][c][n] + accbuf[3][c][n];
        o[j] = g2 * s + xt[base + n];
      }
      *(f32x4*)(out2 + base + g * 4) = o;
    }
  }
}

// ---------------------------------------------------------------------------
extern "C" void kernel_launch(void* const* d_in, const int* in_sizes, int n_in,
                              void* d_out, int out_size, void* d_ws, size_t ws_size,
                              hipStream_t stream) {
  const float* x1  = (const float*)d_in[0];
  const float* x2  = (const float*)d_in[1];
  const float* x3  = (const float*)d_in[2];
  const float* xt  = (const float*)d_in[3];
  const float* Wq  = (const float*)d_in[4];
  const float* bq  = (const float*)d_in[5];
  const float* Wk  = (const float*)d_in[6];
  const float* bk  = (const float*)d_in[7];
  const float* Wk2 = (const float*)d_in[8];
  const float* bk2 = (const float*)d_in[9];
  const float* Wv  = (const float*)d_in[10];
  const float* bv  = (const float*)d_in[11];
  const float* Wv2 = (const float*)d_in[12];
  const float* bv2 = (const float*)d_in[13];
  const float* gamma  = (const float*)d_in[14];
  const float* gamma2 = (const float*)d_in[15];

  float* outp = (float*)d_out;
  float* attn = outp;                                   // B*N*N
  float* out1 = outp + (size_t)Bn * Nn * Nn;            // B*C*N
  float* out2 = out1 + (size_t)Bn * Cn * Nn;

  _Float16* qt  = (_Float16*)d_ws;                      // B*N*CQ f16
  _Float16* k1t = qt + (size_t)Bn * Nn * CQn;
  _Float16* k2t = k1t + (size_t)Bn * Nn * CQn;
  _Float16* v   = k2t + (size_t)Bn * Nn * CQn;          // B*C*N f16
  _Float16* vt  = v + (size_t)Bn * Cn * Nn;

  proj_qk<<<dim3(Nn / 64, Bn, 3), 256, 0, stream>>>(x1, x2, x3, Wq, bq, Wk, bk, Wk2, bk2,
                                                    qt, k1t, k2t);
  proj_v<<<dim3(Nn / 32, Bn, 2), 256, 0, stream>>>(x3, xt, Wv, bv, Wv2, bv2, v, vt);
  attn_fused<<<dim3(Bn * Nn / 16), 256, 0, stream>>>(qt, k1t, k2t, v, vt, x3, xt,
                                                     gamma, gamma2, attn, out1, out2);
}

// Round 4
// 1097.510 us; speedup vs baseline: 1.0290x; 1.0201x over previous
//
#include <hip/hip_runtime.h>

#define Bn 4
#define Cn 256
#define CQn 64
#define Nn 4096
#define NP 4104   // pLds row stride in halves: 8208 B = 16B-aligned, bank-stride 4

using f32x4  = __attribute__((ext_vector_type(4))) float;
using half4  = __attribute__((ext_vector_type(4))) _Float16;
using half8  = __attribute__((ext_vector_type(8))) _Float16;

#define MFMA_F16(a, b, c)  __builtin_amdgcn_mfma_f32_16x16x32_f16((a), (b), (c), 0, 0, 0)

// ---------------------------------------------------------------------------
// P1: q/k1/k2 projections. out_t[b][n][o] = sum_c W[o][c] x[b][c][n] + bias[o]
// stored f16, layout (B, N, 64). blockIdx.z selects proj (0:q<-x3, 1:k1<-x1, 2:k2<-x2).
// ---------------------------------------------------------------------------
__global__ __launch_bounds__(256) void proj_qk(
    const float* __restrict__ x1, const float* __restrict__ x2,
    const float* __restrict__ x3,
    const float* __restrict__ Wq, const float* __restrict__ bq,
    const float* __restrict__ Wk, const float* __restrict__ bk,
    const float* __restrict__ Wk2, const float* __restrict__ bk2,
    _Float16* __restrict__ qt, _Float16* __restrict__ k1t, _Float16* __restrict__ k2t)
{
  const int p = blockIdx.z;
  const float* x    = (p == 0) ? x3 : (p == 1) ? x1 : x2;
  const float* W    = (p == 0) ? Wq : (p == 1) ? Wk : Wk2;
  const float* bias = (p == 0) ? bq : (p == 1) ? bk : bk2;
  _Float16* out     = (p == 0) ? qt : (p == 1) ? k1t : k2t;

  const int b = blockIdx.y;
  const int n0 = blockIdx.x * 64;
  const int tid = threadIdx.x;
  const int w = tid >> 6, lane = tid & 63, quad = lane >> 4, l16 = lane & 15;
  const int n_row = n0 + w * 16 + l16;  // A row
  const float* xb = x + (size_t)b * Cn * Nn;

  f32x4 acc[4] = {};
  for (int kst = 0; kst < 8; ++kst) {
    const int c = kst * 32 + quad * 8;
    half8 a;
#pragma unroll
    for (int j = 0; j < 8; ++j) a[j] = (_Float16)xb[(size_t)(c + j) * Nn + n_row];
#pragma unroll
    for (int s = 0; s < 4; ++s) {
      const int o = s * 16 + l16;
      const f32x4 w0 = *(const f32x4*)(W + (size_t)o * Cn + c);
      const f32x4 w1 = *(const f32x4*)(W + (size_t)o * Cn + c + 4);
      half8 bf;
#pragma unroll
      for (int j = 0; j < 4; ++j) { bf[j] = (_Float16)w0[j]; bf[4 + j] = (_Float16)w1[j]; }
      acc[s] = MFMA_F16(a, bf, acc[s]);
    }
  }
#pragma unroll
  for (int s = 0; s < 4; ++s) {
    const int o = s * 16 + l16;
    const float bb = bias[o];
#pragma unroll
    for (int r = 0; r < 4; ++r) {
      const int n = n0 + w * 16 + quad * 4 + r;  // D row
      out[((size_t)b * Nn + n) * CQn + o] = (_Float16)(acc[s][r] + bb);
    }
  }
}

// ---------------------------------------------------------------------------
// P2: v/vt projections. out[b][o][n] = sum_c W[o][c] x[b][c][n] + bias[o]
// f16, natural layout (B, C, N). blockIdx.z: 0: v<-x3, 1: vt<-xt.
// ---------------------------------------------------------------------------
__global__ __launch_bounds__(256) void proj_v(
    const float* __restrict__ x3, const float* __restrict__ xt,
    const float* __restrict__ Wv, const float* __restrict__ bv,
    const float* __restrict__ Wv2, const float* __restrict__ bv2,
    _Float16* __restrict__ v, _Float16* __restrict__ vt)
{
  const int p = blockIdx.z;
  const float* x    = p ? xt : x3;
  const float* W    = p ? Wv2 : Wv;
  const float* bias = p ? bv2 : bv;
  _Float16* out     = p ? vt : v;

  const int b = blockIdx.y;
  const int n0 = blockIdx.x * 32;
  const int tid = threadIdx.x;
  const int w = tid >> 6, lane = tid & 63, quad = lane >> 4, l16 = lane & 15;
  const float* xb = x + (size_t)b * Cn * Nn;

  f32x4 acc[4][2] = {};
  for (int kst = 0; kst < 8; ++kst) {
    const int c = kst * 32 + quad * 8;
    half8 bfr[2];
#pragma unroll
    for (int t = 0; t < 2; ++t) {
      const int n = n0 + t * 16 + l16;
#pragma unroll
      for (int j = 0; j < 8; ++j) bfr[t][j] = (_Float16)xb[(size_t)(c + j) * Nn + n];
    }
#pragma unroll
    for (int s = 0; s < 4; ++s) {
      const int o = w * 64 + s * 16 + l16;
      const f32x4 w0 = *(const f32x4*)(W + (size_t)o * Cn + c);
      const f32x4 w1 = *(const f32x4*)(W + (size_t)o * Cn + c + 4);
      half8 a;
#pragma unroll
      for (int j = 0; j < 4; ++j) { a[j] = (_Float16)w0[j]; a[4 + j] = (_Float16)w1[j]; }
#pragma unroll
      for (int t = 0; t < 2; ++t) acc[s][t] = MFMA_F16(a, bfr[t], acc[s][t]);
    }
  }
#pragma unroll
  for (int s = 0; s < 4; ++s) {
#pragma unroll
    for (int r = 0; r < 4; ++r) {
      const int o = w * 64 + s * 16 + quad * 4 + r;  // D row
      const float bb = bias[o];
#pragma unroll
      for (int t = 0; t < 2; ++t) {
        const int n = n0 + t * 16 + l16;  // D col
        out[((size_t)b * Cn + o) * Nn + n] = (_Float16)(acc[s][t][r] + bb);
      }
    }
  }
}

// ---------------------------------------------------------------------------
// Fused v2: one 1024-thread block (16 waves, 4/SIMD) per 16 attn rows.
// LDS: p-tile 16 x 4104 f16 (128 KB) + accbuf + reductions = ~151 KB.
//  pass1: waves split m 16-way (256 each): l1,l2 partials -> LDS reduce.
//  pass2: recompute S, pp=exp(a1+a2) -> pLds (f16); L partials -> reduce.
//  pass3: normalize pLds in place; write the ONLY attn HBM traffic (f32).
//  PV: waves = 4 m-chunks x 4 c-chunks; B-frags via ds_read_b128 from pLds;
//      deterministic 4-round LDS reduce into accbuf; epilogue out1 then out2.
// ---------------------------------------------------------------------------
__global__ __launch_bounds__(1024, 4) void attn_fused(
    const _Float16* __restrict__ qt, const _Float16* __restrict__ k1t,
    const _Float16* __restrict__ k2t, const _Float16* __restrict__ v,
    const _Float16* __restrict__ vt,
    const float* __restrict__ x3, const float* __restrict__ xt,
    const float* __restrict__ gamma, const float* __restrict__ gamma2,
    float* __restrict__ attn, float* __restrict__ out1, float* __restrict__ out2)
{
  __shared__ _Float16 pLds[16][NP];     // 131,328 B
  __shared__ float accbuf[256][17];     // 17,408 B
  __shared__ float red[16][2][16];      // 2,048 B
  __shared__ float rLs[16];

  const int i = blockIdx.x;
  const int b = (i & 7) >> 1;                      // batch pinned to XCD pair
  const int nt = ((i >> 3) << 1) | (i & 1);        // 0..255
  const int n0 = nt * 16;
  const int tid = threadIdx.x;
  const int w = tid >> 6, lane = tid & 63, quad = lane >> 4, l16 = lane & 15;
  const int m_lo = w * 256;                        // this wave's m-chunk (pass1/2/3)

  // zero accbuf (used much later; syncs in between guarantee visibility)
  for (int j = tid; j < 256 * 17; j += 1024) ((float*)accbuf)[j] = 0.f;

  const _Float16* qrow = qt + ((size_t)b * Nn + n0 + l16) * CQn;
  const half8 aq0 = *(const half8*)(qrow + quad * 8);
  const half8 aq1 = *(const half8*)(qrow + 32 + quad * 8);
  const _Float16* k1b = k1t + (size_t)b * Nn * CQn;
  const _Float16* k2b = k2t + (size_t)b * Nn * CQn;

  // ---- pass 1: partial row sums of exp(S1), exp(S2) over own 256-m chunk
  float l1a[4] = {0.f, 0.f, 0.f, 0.f}, l2a[4] = {0.f, 0.f, 0.f, 0.f};
#pragma unroll 4
  for (int mi = 0; mi < 16; ++mi) {
    const int m0 = m_lo + mi * 16;
    const _Float16* k1r = k1b + (size_t)(m0 + l16) * CQn;
    const _Float16* k2r = k2b + (size_t)(m0 + l16) * CQn;
    f32x4 S1 = {};
    S1 = MFMA_F16(aq0, *(const half8*)(k1r + quad * 8), S1);
    S1 = MFMA_F16(aq1, *(const half8*)(k1r + 32 + quad * 8), S1);
    f32x4 S2 = {};
    S2 = MFMA_F16(aq0, *(const half8*)(k2r + quad * 8), S2);
    S2 = MFMA_F16(aq1, *(const half8*)(k2r + 32 + quad * 8), S2);
#pragma unroll
    for (int r = 0; r < 4; ++r) { l1a[r] += __expf(S1[r]); l2a[r] += __expf(S2[r]); }
  }
#pragma unroll
  for (int r = 0; r < 4; ++r) {
#pragma unroll
    for (int off = 1; off < 16; off <<= 1) {
      l1a[r] += __shfl_xor(l1a[r], off);
      l2a[r] += __shfl_xor(l2a[r], off);
    }
  }
  if (l16 == 0) {
#pragma unroll
    for (int r = 0; r < 4; ++r) { red[w][0][quad * 4 + r] = l1a[r]; red[w][1][quad * 4 + r] = l2a[r]; }
  }
  __syncthreads();
  float lg1[4], lg2[4];
#pragma unroll
  for (int r = 0; r < 4; ++r) {
    const int n = quad * 4 + r;
    float s1 = 0.f, s2 = 0.f;
#pragma unroll
    for (int ww = 0; ww < 16; ++ww) { s1 += red[ww][0][n]; s2 += red[ww][1][n]; }
    lg1[r] = __logf(s1); lg2[r] = __logf(s2);
  }
  __syncthreads();   // red reused for L below

  // ---- pass 2: pp = exp(exp(S1-lg1)+exp(S2-lg2)) -> pLds (f16); L partials
  float La[4] = {0.f, 0.f, 0.f, 0.f};
#pragma unroll 2
  for (int mi = 0; mi < 16; ++mi) {
    const int m0 = m_lo + mi * 16;
    const _Float16* k1r = k1b + (size_t)(m0 + l16) * CQn;
    const _Float16* k2r = k2b + (size_t)(m0 + l16) * CQn;
    f32x4 S1 = {};
    S1 = MFMA_F16(aq0, *(const half8*)(k1r + quad * 8), S1);
    S1 = MFMA_F16(aq1, *(const half8*)(k1r + 32 + quad * 8), S1);
    f32x4 S2 = {};
    S2 = MFMA_F16(aq0, *(const half8*)(k2r + quad * 8), S2);
    S2 = MFMA_F16(aq1, *(const half8*)(k2r + 32 + quad * 8), S2);
#pragma unroll
    for (int r = 0; r < 4; ++r) {
      const float a1 = __expf(S1[r] - lg1[r]);
      const float a2 = __expf(S2[r] - lg2[r]);
      const float pp = __expf(a1 + a2);
      La[r] += pp;
      pLds[quad * 4 + r][m0 + l16] = (_Float16)pp;
    }
  }
#pragma unroll
  for (int r = 0; r < 4; ++r) {
#pragma unroll
    for (int off = 1; off < 16; off <<= 1) La[r] += __shfl_xor(La[r], off);
  }
  if (l16 == 0) {
#pragma unroll
    for (int r = 0; r < 4; ++r) red[w][0][quad * 4 + r] = La[r];
  }
  __syncthreads();
  if (tid < 16) {
    float s = 0.f;
#pragma unroll
    for (int ww = 0; ww < 16; ++ww) s += red[ww][0][tid];
    rLs[tid] = 1.0f / s;
  }
  __syncthreads();

  // ---- pass 3: normalize pLds in place; write attn (f32) to HBM (only write)
#pragma unroll 4
  for (int row = 0; row < 16; ++row) {
    const float rl = rLs[row];
    _Float16* pp4 = &pLds[row][m_lo + lane * 4];
    const half4 h = *(const half4*)pp4;
    f32x4 o;
#pragma unroll
    for (int j = 0; j < 4; ++j) o[j] = (float)h[j] * rl;
    *(f32x4*)(attn + ((size_t)b * Nn + n0 + row) * Nn + m_lo + lane * 4) = o;
    half4 hn;
#pragma unroll
    for (int j = 0; j < 4; ++j) hn[j] = (_Float16)o[j];
    *(half4*)pp4 = hn;
  }
  __syncthreads();

  // ---- PV: wave (wm, wc): m in [1024*wm, +1024), c in [64*wc, +64)
  const int wm = w & 3, wc = w >> 2;
  const int cb = wc * 64;
  const _Float16* vb  = v  + (size_t)b * Cn * Nn;
  const _Float16* vtb = vt + (size_t)b * Cn * Nn;
  f32x4 acc1[4] = {}, acc2[4] = {};
  for (int it = 0; it < 32; ++it) {
    const int m0 = wm * 1024 + it * 32;
    const half8 Bf = *(const half8*)(&pLds[l16][m0 + quad * 8]);
#pragma unroll
    for (int s = 0; s < 4; ++s) {
      const half8 A1 = *(const half8*)(vb + (size_t)(cb + s * 16 + l16) * Nn + m0 + quad * 8);
      acc1[s] = MFMA_F16(A1, Bf, acc1[s]);
    }
#pragma unroll
    for (int s = 0; s < 4; ++s) {
      const half8 A2 = *(const half8*)(vtb + (size_t)(cb + s * 16 + l16) * Nn + m0 + quad * 8);
      acc2[s] = MFMA_F16(A2, Bf, acc2[s]);
    }
  }

  // ---- deterministic 4-round cross-wm reduce + epilogue, out1 then out2
#pragma unroll 1
  for (int k = 0; k < 4; ++k) {
    if (wm == k) {
#pragma unroll
      for (int s = 0; s < 4; ++s)
#pragma unroll
        for (int r = 0; r < 4; ++r)
          accbuf[cb + s * 16 + quad * 4 + r][l16] += acc1[s][r];
    }
    __syncthreads();
  }
  {
    const float g1 = gamma[0];
    const int c = tid >> 2, ng = (tid & 3) * 4;
    const size_t base = ((size_t)b * Cn + c) * Nn + n0 + ng;
    f32x4 o;
#pragma unroll
    for (int j = 0; j < 4; ++j) o[j] = g1 * accbuf[c][ng + j] + x3[base + j];
    *(f32x4*)(out1 + base) = o;
  }
  __syncthreads();
  for (int j = tid; j < 256 * 17; j += 1024) ((float*)accbuf)[j] = 0.f;
  __syncthreads();
#pragma unroll 1
  for (int k = 0; k < 4; ++k) {
    if (wm == k) {
#pragma unroll
      for (int s = 0; s < 4; ++s)
#pragma unroll
        for (int r = 0; r < 4; ++r)
          accbuf[cb + s * 16 + quad * 4 + r][l16] += acc2[s][r];
    }
    __syncthreads();
  }
  {
    const float g2 = gamma2[0];
    const int c = tid >> 2, ng = (tid & 3) * 4;
    const size_t base = ((size_t)b * Cn + c) * Nn + n0 + ng;
    f32x4 o;
#pragma unroll
    for (int j = 0; j < 4; ++j) o[j] = g2 * accbuf[c][ng + j] + xt[base + j];
    *(f32x4*)(out2 + base) = o;
  }
}

// ---------------------------------------------------------------------------
extern "C" void kernel_launch(void* const* d_in, const int* in_sizes, int n_in,
                              void* d_out, int out_size, void* d_ws, size_t ws_size,
                              hipStream_t stream) {
  const float* x1  = (const float*)d_in[0];
  const float* x2  = (const float*)d_in[1];
  const float* x3  = (const float*)d_in[2];
  const float* xt  = (const float*)d_in[3];
  const float* Wq  = (const float*)d_in[4];
  const float* bq  = (const float*)d_in[5];
  const float* Wk  = (const float*)d_in[6];
  const float* bk  = (const float*)d_in[7];
  const float* Wk2 = (const float*)d_in[8];
  const float* bk2 = (const float*)d_in[9];
  const float* Wv  = (const float*)d_in[10];
  const float* bv  = (const float*)d_in[11];
  const float* Wv2 = (const float*)d_in[12];
  const float* bv2 = (const float*)d_in[13];
  const float* gamma  = (const float*)d_in[14];
  const float* gamma2 = (const float*)d_in[15];

  float* outp = (float*)d_out;
  float* attn = outp;                                   // B*N*N
  float* out1 = outp + (size_t)Bn * Nn * Nn;            // B*C*N
  float* out2 = out1 + (size_t)Bn * Cn * Nn;

  _Float16* qt  = (_Float16*)d_ws;                      // B*N*CQ f16
  _Float16* k1t = qt + (size_t)Bn * Nn * CQn;
  _Float16* k2t = k1t + (size_t)Bn * Nn * CQn;
  _Float16* v   = k2t + (size_t)Bn * Nn * CQn;          // B*C*N f16
  _Float16* vt  = v + (size_t)Bn * Cn * Nn;

  proj_qk<<<dim3(Nn / 64, Bn, 3), 256, 0, stream>>>(x1, x2, x3, Wq, bq, Wk, bk, Wk2, bk2,
                                                    qt, k1t, k2t);
  proj_v<<<dim3(Nn / 32, Bn, 2), 256, 0, stream>>>(x3, xt, Wv, bv, Wv2, bv2, v, vt);
  attn_fused<<<dim3(Bn * Nn / 16), 1024, 0, stream>>>(qt, k1t, k2t, v, vt, x3, xt,
                                                      gamma, gamma2, attn, out1, out2);
}